// Round 5
// baseline (3469.981 us; speedup 1.0000x reference)
//
#include <hip/hip_runtime.h>
#include <math.h>

typedef unsigned short u16;
typedef unsigned int   u32;

#define S_LEN 4096
#define HID   2048
#define NHEAD 16
#define HD    128
#define NW    1024
#define TOK   8192
#define LN10000 9.2103403719761836f
#define NEG_BIG (-1e30f)

__device__ __forceinline__ float b2f(u16 u){
  union { u32 i; float f; } v; v.i = ((u32)u) << 16; return v.f;
}
__device__ __forceinline__ u16 f2b(float f){
  union { float f; u32 i; } v; v.f = f;
  return (u16)((v.i + 0x7FFFu + ((v.i >> 16) & 1u)) >> 16);
}
__device__ __forceinline__ void unpack8(const u16* p, float* f){
  uint4 v = *(const uint4*)p;
  union { u32 i; float fl; } t;
  t.i = v.x << 16;         f[0] = t.fl;
  t.i = v.x & 0xFFFF0000u; f[1] = t.fl;
  t.i = v.y << 16;         f[2] = t.fl;
  t.i = v.y & 0xFFFF0000u; f[3] = t.fl;
  t.i = v.z << 16;         f[4] = t.fl;
  t.i = v.z & 0xFFFF0000u; f[5] = t.fl;
  t.i = v.w << 16;         f[6] = t.fl;
  t.i = v.w & 0xFFFF0000u; f[7] = t.fl;
}

// ---------------- VALU f32 GEMM ---------------------------------------------------------
// C(M,N) = A(M,K) @ B(K,N). A: f32 or bf16(u16). B: f32. C: bf16(u16) or f32 (templated).
// 64x64 block tile, 256 threads as 16x16, 4x4 micro-tile/thread, BK=16, f32 LDS staging.
template<typename TA, typename TC>
__global__ __launch_bounds__(256) void gemm_valu(const TA* __restrict__ A,
    const float* __restrict__ B, TC* __restrict__ C, int M, int N, int K)
{
  __shared__ float As[64][17];
  __shared__ float Bs[16][68];
  const int tid = threadIdx.x;
  const int bM = blockIdx.y * 64;
  const int bN = blockIdx.x * 64;
  const int tx = tid & 15;        // micro-tile col group
  const int ty = tid >> 4;        // micro-tile row group

  float acc[4][4];
  #pragma unroll
  for (int r = 0; r < 4; r++)
    #pragma unroll
    for (int c = 0; c < 4; c++) acc[r][c] = 0.f;

  for (int k0 = 0; k0 < K; k0 += 16){
    // stage A: 64 rows x 16 k; thread -> (row = tid>>2, kc = (tid&3)*4)
    {
      int row = tid >> 2, kc = (tid & 3) * 4;
      const TA* src = &A[(size_t)(bM + row)*K + k0 + kc];
      float v0, v1, v2, v3;
      if constexpr (sizeof(TA) == 4){
        float4 v = *(const float4*)src;
        v0 = v.x; v1 = v.y; v2 = v.z; v3 = v.w;
      } else {
        v0 = b2f(src[0]); v1 = b2f(src[1]); v2 = b2f(src[2]); v3 = b2f(src[3]);
      }
      As[row][kc+0] = v0; As[row][kc+1] = v1; As[row][kc+2] = v2; As[row][kc+3] = v3;
    }
    // stage B: 16 k x 64 n; thread -> (kr = tid>>4, nc = (tid&15)*4)
    {
      int kr = tid >> 4, nc = (tid & 15) * 4;
      float4 v = *(const float4*)&B[(size_t)(k0 + kr)*N + bN + nc];
      Bs[kr][nc+0] = v.x; Bs[kr][nc+1] = v.y; Bs[kr][nc+2] = v.z; Bs[kr][nc+3] = v.w;
    }
    __syncthreads();
    #pragma unroll
    for (int kk = 0; kk < 16; kk++){
      float a0 = As[ty*4+0][kk], a1 = As[ty*4+1][kk],
            a2 = As[ty*4+2][kk], a3 = As[ty*4+3][kk];
      float b0 = Bs[kk][tx*4+0], b1 = Bs[kk][tx*4+1],
            b2 = Bs[kk][tx*4+2], b3 = Bs[kk][tx*4+3];
      acc[0][0] += a0*b0; acc[0][1] += a0*b1; acc[0][2] += a0*b2; acc[0][3] += a0*b3;
      acc[1][0] += a1*b0; acc[1][1] += a1*b1; acc[1][2] += a1*b2; acc[1][3] += a1*b3;
      acc[2][0] += a2*b0; acc[2][1] += a2*b1; acc[2][2] += a2*b2; acc[2][3] += a2*b3;
      acc[3][0] += a3*b0; acc[3][1] += a3*b1; acc[3][2] += a3*b2; acc[3][3] += a3*b3;
    }
    __syncthreads();
  }
  #pragma unroll
  for (int r = 0; r < 4; r++)
    #pragma unroll
    for (int c = 0; c < 4; c++){
      size_t idx = (size_t)(bM + ty*4 + r)*N + bN + tx*4 + c;
      if constexpr (sizeof(TC) == 4) C[idx] = acc[r][c];
      else                           C[idx] = f2b(acc[r][c]);
    }
}

// ---------------- partial interleaved RoPE on q (bf16 ws), in place ---------------------
__global__ void rope_q_kernel(u16* __restrict__ q){
  int gid = blockIdx.x * 256 + threadIdx.x;   // 8192*16*32 pairs
  int t = gid >> 9;
  int r = gid & 511;
  int h = r >> 5;
  int i = r & 31;
  int pos = t & (S_LEN - 1);
  float freq = expf(-(float)i * (LN10000 / 32.f));
  float ang = (float)pos * freq;
  float sn, cs;
  sincosf(ang, &sn, &cs);
  size_t off = (size_t)t*HID + h*HD + 64 + 2*i;
  float a  = b2f(q[off]);
  float bb = b2f(q[off+1]);
  q[off]   = f2b(a*cs - bb*sn);
  q[off+1] = f2b(a*sn + bb*cs);
}

// ---------------- overlapped pooling + k RoPE -------------------------------------------
__global__ void pool_rope_k(const u16* __restrict__ kv, const u16* __restrict__ gate,
                            const float* __restrict__ ape, u16* __restrict__ krot,
                            u16* __restrict__ vout){
  const int d = threadIdx.x;   // 0..127
  const int w = blockIdx.x;    // 0..1023
  const int b = blockIdx.y;
  __shared__ float sh[HD];
  const bool hasprev = (w > 0);
  float gc[4], vc[4], gp[4], vp[4];
  float m = NEG_BIG;
  #pragma unroll
  for (int r = 0; r < 4; r++){
    size_t t = (size_t)(b*S_LEN + w*4 + r)*256;
    vc[r] = b2f(kv[t + 128 + d]);
    gc[r] = b2f(gate[t + 128 + d]) + ape[r*256 + 128 + d];
    m = fmaxf(m, gc[r]);
  }
  if (hasprev){
    #pragma unroll
    for (int r = 0; r < 4; r++){
      size_t t = (size_t)(b*S_LEN + (w-1)*4 + r)*256;
      vp[r] = b2f(kv[t + d]);
      gp[r] = b2f(gate[t + d]) + ape[r*256 + d];
      m = fmaxf(m, gp[r]);
    }
  }
  float s = 0.f, acc = 0.f;
  #pragma unroll
  for (int r = 0; r < 4; r++){
    float e = __expf(gc[r] - m); s += e; acc += e*vc[r];
  }
  if (hasprev){
    #pragma unroll
    for (int r = 0; r < 4; r++){
      float e = __expf(gp[r] - m); s += e; acc += e*vp[r];
    }
  }
  float pooled = acc / s;
  sh[d] = pooled;
  __syncthreads();
  float kr = pooled;
  if (d >= 64){
    int i = (d - 64) >> 1;
    float freq = expf(-(float)i * (LN10000 / 32.f));
    float ang = (float)(4*w) * freq;
    float sn, cs;
    sincosf(ang, &sn, &cs);
    if ((d & 1) == 0) kr = sh[d]*cs - sh[d+1]*sn;
    else              kr = sh[d-1]*sn + sh[d]*cs;
  }
  size_t o = (size_t)(b*NW + w)*HD + d;
  krot[o] = f2b(kr);
  vout[o] = f2b(pooled);
}

// ---------------- flash-style attention (VALU f32) --------------------------------------
#define QT 32
#define KT 64
#define QSTR 136
#define KSTR 136
#define SSTR 68
#define ATT_SCALE 0.088388347648318447f

__global__ __launch_bounds__(256) void attn_kernel(
    const u16* __restrict__ qbuf, const u16* __restrict__ krot,
    const u16* __restrict__ vbuf, const float* __restrict__ sinks,
    u16* __restrict__ attnbuf)
{
  __shared__ u16 Qs[QT*QSTR];
  __shared__ u16 Ks[KT*KSTR];
  __shared__ u16 Vs[KT*KSTR];
  __shared__ float Ssc[QT*SSTR];
  __shared__ float red[256];
  __shared__ float mrow[QT], lrow[QT], arow[QT];

  const int tid = threadIdx.x;
  const int q0  = blockIdx.x * QT;
  const int h   = blockIdx.y;
  const int b   = blockIdx.z;

  for (int c = tid; c < QT*16; c += 256){
    int qi = c >> 4, ch = c & 15;
    *(uint4*)&Qs[qi*QSTR + ch*8] =
      *(const uint4*)&qbuf[(size_t)(b*S_LEN + q0 + qi)*HID + h*HD + ch*8];
  }
  if (tid < QT){ mrow[tid] = NEG_BIG; lrow[tid] = 0.f; }

  float O[16];
  #pragma unroll
  for (int i = 0; i < 16; i++) O[i] = 0.f;

  const int qi   = tid >> 3;
  const int kj   = tid & 7;
  const int dseg = (tid & 7) * 16;
  const int qg   = q0 + qi;

  const int kmax_tile = (q0 + QT - 1 - 3) >> 2;
  int nchunk = (kmax_tile >> 6) + 1;
  if (nchunk > NW/KT) nchunk = NW/KT;

  __syncthreads();

  for (int ch = 0; ch < nchunk; ch++){
    const int kc0 = ch * KT;
    for (int c = tid; c < KT*16; c += 256){
      int kl = c >> 4, cc = c & 15;
      size_t g = (size_t)(b*NW + kc0 + kl)*HD + cc*8;
      *(uint4*)&Ks[kl*KSTR + cc*8] = *(const uint4*)&krot[g];
      *(uint4*)&Vs[kl*KSTR + cc*8] = *(const uint4*)&vbuf[g];
    }
    __syncthreads();

    float sacc[8];
    #pragma unroll
    for (int j = 0; j < 8; j++) sacc[j] = 0.f;
    for (int d0 = 0; d0 < HD; d0 += 8){
      float qf[8];
      unpack8(&Qs[qi*QSTR + d0], qf);
      #pragma unroll
      for (int j = 0; j < 8; j++){
        float kf[8];
        unpack8(&Ks[(kj + 8*j)*KSTR + d0], kf);
        #pragma unroll
        for (int i = 0; i < 8; i++) sacc[j] += qf[i]*kf[i];
      }
    }
    float lmax = NEG_BIG;
    #pragma unroll
    for (int j = 0; j < 8; j++){
      int kg = kc0 + kj + 8*j;
      float s = (qg >= 4*kg + 3) ? sacc[j]*ATT_SCALE : NEG_BIG;
      Ssc[qi*SSTR + kj + 8*j] = s;
      lmax = fmaxf(lmax, s);
    }
    red[qi*8 + kj] = lmax;
    __syncthreads();

    if (tid < QT){
      float mold = mrow[tid];
      float mx = mold;
      #pragma unroll
      for (int j = 0; j < 8; j++) mx = fmaxf(mx, red[tid*8 + j]);
      arow[tid] = __expf(mold - mx);
      mrow[tid] = mx;
    }
    __syncthreads();

    {
      float mloc = mrow[qi];
      float ls = 0.f;
      #pragma unroll
      for (int j = 0; j < 8; j++){
        int idx = qi*SSTR + kj + 8*j;
        float s = Ssc[idx];
        float p = __expf(s - mloc);
        Ssc[idx] = p;
        ls += p;
      }
      red[qi*8 + kj] = ls;
    }
    __syncthreads();

    if (tid < QT){
      float sum = 0.f;
      #pragma unroll
      for (int j = 0; j < 8; j++) sum += red[tid*8 + j];
      lrow[tid] = lrow[tid]*arow[tid] + sum;
    }
    {
      float alpha = arow[qi];
      #pragma unroll
      for (int i = 0; i < 16; i++) O[i] *= alpha;
      for (int kl = 0; kl < KT; kl++){
        float p = Ssc[qi*SSTR + kl];
        float vf[16];
        unpack8(&Vs[kl*KSTR + dseg], vf);
        unpack8(&Vs[kl*KSTR + dseg + 8], vf + 8);
        #pragma unroll
        for (int i = 0; i < 16; i++) O[i] += p * vf[i];
      }
    }
    __syncthreads();
  }

  float m = mrow[qi], l = lrow[qi];
  float snk = sinks[h];
  float mf = fmaxf(m, snk);
  float denom = l * __expf(m - mf) + __expf(snk - mf);
  float sc = __expf(m - mf) / denom;
  size_t o = (size_t)(b*S_LEN + qg)*HID + h*HD + dseg;
  #pragma unroll
  for (int i = 0; i < 16; i++) attnbuf[o + i] = f2b(O[i] * sc);
}

// ---------------------------------------------------------------------------------------
extern "C" void kernel_launch(void* const* d_in, const int* in_sizes, int n_in,
                              void* d_out, int out_size, void* d_ws, size_t ws_size,
                              hipStream_t stream)
{
  const float* hidden = (const float*)d_in[0];
  const float* wq     = (const float*)d_in[1];
  const float* wkv    = (const float*)d_in[2];
  const float* wgate  = (const float*)d_in[3];
  const float* ape    = (const float*)d_in[4];
  const float* sinks  = (const float*)d_in[5];
  const float* wo     = (const float*)d_in[6];

  u16* qbuf    = (u16*)d_ws;                        // 8192*2048 bf16
  u16* kvbuf   = qbuf    + (size_t)TOK*HID;         // 8192*256
  u16* gatebuf = kvbuf   + (size_t)TOK*256;         // 8192*256
  u16* krot    = gatebuf + (size_t)TOK*256;         // 2*1024*128
  u16* vbuf    = krot    + (size_t)2*NW*HD;         // 2*1024*128
  u16* attnbuf = vbuf    + (size_t)2*NW*HD;         // 8192*2048

  gemm_valu<float,u16><<<dim3(HID/64, TOK/64), 256, 0, stream>>>(hidden, wq,    qbuf,    TOK, HID, HID);
  gemm_valu<float,u16><<<dim3(256/64, TOK/64), 256, 0, stream>>>(hidden, wkv,   kvbuf,   TOK, 256, HID);
  gemm_valu<float,u16><<<dim3(256/64, TOK/64), 256, 0, stream>>>(hidden, wgate, gatebuf, TOK, 256, HID);
  rope_q_kernel<<<(TOK*NHEAD*32)/256, 256, 0, stream>>>(qbuf);
  pool_rope_k<<<dim3(NW, 2), 128, 0, stream>>>(kvbuf, gatebuf, ape, krot, vbuf);
  attn_kernel<<<dim3(S_LEN/QT, NHEAD, 2), 256, 0, stream>>>(qbuf, krot, vbuf, sinks, attnbuf);
  // OUTPUT IS F32 (reference returns float32; "else float*" rule). This was the bug:
  // writing bf16 pairs into an f32 buffer made checker elem j ~ our elem 2j+1 ->
  // same-scale decorrelated readback, absmax ~= sqrt(2)*max|ref| = 1.95. Observed: 1.945/1.953.
  gemm_valu<u16,float><<<dim3(HID/64, TOK/64), 256, 0, stream>>>(attnbuf, wo, (float*)d_out, TOK, HID, HID);
}

// Round 6
// 2183.107 us; speedup vs baseline: 1.5895x; 1.5895x over previous
//
#include <hip/hip_runtime.h>
#include <math.h>

typedef unsigned short u16;
typedef unsigned int   u32;
typedef __bf16 bf16x8 __attribute__((ext_vector_type(8)));
typedef float  f32x4  __attribute__((ext_vector_type(4)));

#define S_LEN 4096
#define HID   2048
#define NHEAD 16
#define HD    128
#define NW    1024
#define TOK   8192
#define LN10000 9.2103403719761836f
#define NEG_BIG (-1e30f)

__device__ __forceinline__ float b2f(u16 u){
  union { u32 i; float f; } v; v.i = ((u32)u) << 16; return v.f;
}
__device__ __forceinline__ u16 f2b(float f){
  union { float f; u32 i; } v; v.f = f;
  return (u16)((v.i + 0x7FFFu + ((v.i >> 16) & 1u)) >> 16);
}
__device__ __forceinline__ void unpack8(const u16* p, float* f){
  uint4 v = *(const uint4*)p;
  union { u32 i; float fl; } t;
  t.i = v.x << 16;         f[0] = t.fl;
  t.i = v.x & 0xFFFF0000u; f[1] = t.fl;
  t.i = v.y << 16;         f[2] = t.fl;
  t.i = v.y & 0xFFFF0000u; f[3] = t.fl;
  t.i = v.z << 16;         f[4] = t.fl;
  t.i = v.z & 0xFFFF0000u; f[5] = t.fl;
  t.i = v.w << 16;         f[6] = t.fl;
  t.i = v.w & 0xFFFF0000u; f[7] = t.fl;
}

// ---------------- MFMA GEMM: C(M,N) = A(M,K) @ B(K,N) -----------------------------------
// A: f32 (inputs) or bf16/u16 (ws). B: f32 (weights). C: bf16/u16 or f32 (templated).
// 128x128 tile, BK=32, 4 waves 2x2 (64x64 each), mfma_f32_16x16x32_bf16, convert at stage.
// A-frag: lane holds A[m=lane&15][k=quad*8+j]; B staged transposed ([n][k]) so the same
// contiguous-16B read gives B[n=lane&15][k=quad*8+j]. C/D: col=lane&15, row=quad*4+reg
// (m89/m91-verified). LDS ld 32->40 (80B=5*16B: b128-aligned, 2-way banks only = free).
// Exonerated by R3/R4 A/B: VALU-f32 GEMM reproduced this GEMM's output to 0.4%.
template<typename TA, typename TC>
__global__ __launch_bounds__(256) void gemm_any(const TA* __restrict__ A,
    const float* __restrict__ Bw, TC* __restrict__ C, int M, int N, int K)
{
  __shared__ u16 As[128*40];
  __shared__ u16 Bs[128*40];
  const int tid  = threadIdx.x;
  const int bM   = blockIdx.y * 128;
  const int bN   = blockIdx.x * 128;
  const int lane = tid & 63;
  const int wid  = tid >> 6;
  const int wm   = wid >> 1, wn = wid & 1;
  const int lrow = lane & 15, quad = lane >> 4;

  f32x4 acc[4][4];
  #pragma unroll
  for (int i = 0; i < 4; i++)
    #pragma unroll
    for (int j = 0; j < 4; j++)
      #pragma unroll
      for (int r = 0; r < 4; r++) acc[i][j][r] = 0.f;

  for (int k0 = 0; k0 < K; k0 += 32){
    // stage A: 128 rows x 32 k, 4 elems/thread/iter
    #pragma unroll
    for (int i = 0; i < 4; i++){
      int c = tid + i*256;
      int row = c >> 3, kc = (c & 7) * 4;
      u16 tmp[4];
      if constexpr (sizeof(TA) == 4){
        float4 v = *(const float4*)&A[(size_t)(bM + row)*K + k0 + kc];
        tmp[0] = f2b(v.x); tmp[1] = f2b(v.y); tmp[2] = f2b(v.z); tmp[3] = f2b(v.w);
      } else {
        *(uint2*)tmp = *(const uint2*)&A[(size_t)(bM + row)*K + k0 + kc];
      }
      *(uint2*)&As[row*40 + kc] = *(uint2*)tmp;
    }
    // stage B transposed: 32 k-rows x 128 n (f32, coalesced float4), scatter to Bs[n][k]
    #pragma unroll
    for (int i = 0; i < 4; i++){
      int c = tid + i*256;
      int kr = c >> 5, nc = (c & 31) * 4;
      float4 v = *(const float4*)&Bw[(size_t)(k0 + kr)*N + bN + nc];
      Bs[(nc+0)*40 + kr] = f2b(v.x);
      Bs[(nc+1)*40 + kr] = f2b(v.y);
      Bs[(nc+2)*40 + kr] = f2b(v.z);
      Bs[(nc+3)*40 + kr] = f2b(v.w);
    }
    __syncthreads();
    bf16x8 af[4], bfv[4];
    #pragma unroll
    for (int mf = 0; mf < 4; mf++)
      af[mf] = *(const bf16x8*)&As[(wm*64 + mf*16 + lrow)*40 + quad*8];
    #pragma unroll
    for (int nf = 0; nf < 4; nf++)
      bfv[nf] = *(const bf16x8*)&Bs[(wn*64 + nf*16 + lrow)*40 + quad*8];
    #pragma unroll
    for (int mf = 0; mf < 4; mf++)
      #pragma unroll
      for (int nf = 0; nf < 4; nf++)
        acc[mf][nf] = __builtin_amdgcn_mfma_f32_16x16x32_bf16(af[mf], bfv[nf], acc[mf][nf], 0, 0, 0);
    __syncthreads();
  }
  #pragma unroll
  for (int mf = 0; mf < 4; mf++){
    #pragma unroll
    for (int nf = 0; nf < 4; nf++){
      int gcol = bN + wn*64 + nf*16 + lrow;
      #pragma unroll
      for (int r = 0; r < 4; r++){
        int grow = bM + wm*64 + mf*16 + quad*4 + r;
        size_t idx = (size_t)grow*N + gcol;
        if constexpr (sizeof(TC) == 4) C[idx] = acc[mf][nf][r];
        else                           C[idx] = f2b(acc[mf][nf][r]);
      }
    }
  }
}

// ---------------- partial interleaved RoPE on q (bf16 ws), in place ---------------------
__global__ void rope_q_kernel(u16* __restrict__ q){
  int gid = blockIdx.x * 256 + threadIdx.x;   // 8192*16*32 pairs
  int t = gid >> 9;
  int r = gid & 511;
  int h = r >> 5;
  int i = r & 31;
  int pos = t & (S_LEN - 1);
  float freq = expf(-(float)i * (LN10000 / 32.f));
  float ang = (float)pos * freq;
  float sn, cs;
  sincosf(ang, &sn, &cs);
  size_t off = (size_t)t*HID + h*HD + 64 + 2*i;
  float a  = b2f(q[off]);
  float bb = b2f(q[off+1]);
  q[off]   = f2b(a*cs - bb*sn);
  q[off+1] = f2b(a*sn + bb*cs);
}

// ---------------- overlapped pooling + k RoPE -------------------------------------------
__global__ void pool_rope_k(const u16* __restrict__ kv, const u16* __restrict__ gate,
                            const float* __restrict__ ape, u16* __restrict__ krot,
                            u16* __restrict__ vout){
  const int d = threadIdx.x;   // 0..127
  const int w = blockIdx.x;    // 0..1023
  const int b = blockIdx.y;
  __shared__ float sh[HD];
  const bool hasprev = (w > 0);
  float gc[4], vc[4], gp[4], vp[4];
  float m = NEG_BIG;
  #pragma unroll
  for (int r = 0; r < 4; r++){
    size_t t = (size_t)(b*S_LEN + w*4 + r)*256;
    vc[r] = b2f(kv[t + 128 + d]);
    gc[r] = b2f(gate[t + 128 + d]) + ape[r*256 + 128 + d];
    m = fmaxf(m, gc[r]);
  }
  if (hasprev){
    #pragma unroll
    for (int r = 0; r < 4; r++){
      size_t t = (size_t)(b*S_LEN + (w-1)*4 + r)*256;
      vp[r] = b2f(kv[t + d]);
      gp[r] = b2f(gate[t + d]) + ape[r*256 + d];
      m = fmaxf(m, gp[r]);
    }
  }
  float s = 0.f, acc = 0.f;
  #pragma unroll
  for (int r = 0; r < 4; r++){
    float e = __expf(gc[r] - m); s += e; acc += e*vc[r];
  }
  if (hasprev){
    #pragma unroll
    for (int r = 0; r < 4; r++){
      float e = __expf(gp[r] - m); s += e; acc += e*vp[r];
    }
  }
  float pooled = acc / s;
  sh[d] = pooled;
  __syncthreads();
  float kr = pooled;
  if (d >= 64){
    int i = (d - 64) >> 1;
    float freq = expf(-(float)i * (LN10000 / 32.f));
    float ang = (float)(4*w) * freq;
    float sn, cs;
    sincosf(ang, &sn, &cs);
    if ((d & 1) == 0) kr = sh[d]*cs - sh[d+1]*sn;
    else              kr = sh[d-1]*sn + sh[d]*cs;
  }
  size_t o = (size_t)(b*NW + w)*HD + d;
  krot[o] = f2b(kr);
  vout[o] = f2b(pooled);
}

// ---------------- flash-style attention (VALU f32, unchanged from passing R5) -----------
#define QT 32
#define KT 64
#define QSTR 136
#define KSTR 136
#define SSTR 68
#define ATT_SCALE 0.088388347648318447f

__global__ __launch_bounds__(256) void attn_kernel(
    const u16* __restrict__ qbuf, const u16* __restrict__ krot,
    const u16* __restrict__ vbuf, const float* __restrict__ sinks,
    u16* __restrict__ attnbuf)
{
  __shared__ u16 Qs[QT*QSTR];
  __shared__ u16 Ks[KT*KSTR];
  __shared__ u16 Vs[KT*KSTR];
  __shared__ float Ssc[QT*SSTR];
  __shared__ float red[256];
  __shared__ float mrow[QT], lrow[QT], arow[QT];

  const int tid = threadIdx.x;
  const int q0  = blockIdx.x * QT;
  const int h   = blockIdx.y;
  const int b   = blockIdx.z;

  for (int c = tid; c < QT*16; c += 256){
    int qi = c >> 4, ch = c & 15;
    *(uint4*)&Qs[qi*QSTR + ch*8] =
      *(const uint4*)&qbuf[(size_t)(b*S_LEN + q0 + qi)*HID + h*HD + ch*8];
  }
  if (tid < QT){ mrow[tid] = NEG_BIG; lrow[tid] = 0.f; }

  float O[16];
  #pragma unroll
  for (int i = 0; i < 16; i++) O[i] = 0.f;

  const int qi   = tid >> 3;
  const int kj   = tid & 7;
  const int dseg = (tid & 7) * 16;
  const int qg   = q0 + qi;

  const int kmax_tile = (q0 + QT - 1 - 3) >> 2;
  int nchunk = (kmax_tile >> 6) + 1;
  if (nchunk > NW/KT) nchunk = NW/KT;

  __syncthreads();

  for (int ch = 0; ch < nchunk; ch++){
    const int kc0 = ch * KT;
    for (int c = tid; c < KT*16; c += 256){
      int kl = c >> 4, cc = c & 15;
      size_t g = (size_t)(b*NW + kc0 + kl)*HD + cc*8;
      *(uint4*)&Ks[kl*KSTR + cc*8] = *(const uint4*)&krot[g];
      *(uint4*)&Vs[kl*KSTR + cc*8] = *(const uint4*)&vbuf[g];
    }
    __syncthreads();

    float sacc[8];
    #pragma unroll
    for (int j = 0; j < 8; j++) sacc[j] = 0.f;
    for (int d0 = 0; d0 < HD; d0 += 8){
      float qf[8];
      unpack8(&Qs[qi*QSTR + d0], qf);
      #pragma unroll
      for (int j = 0; j < 8; j++){
        float kf[8];
        unpack8(&Ks[(kj + 8*j)*KSTR + d0], kf);
        #pragma unroll
        for (int i = 0; i < 8; i++) sacc[j] += qf[i]*kf[i];
      }
    }
    float lmax = NEG_BIG;
    #pragma unroll
    for (int j = 0; j < 8; j++){
      int kg = kc0 + kj + 8*j;
      float s = (qg >= 4*kg + 3) ? sacc[j]*ATT_SCALE : NEG_BIG;
      Ssc[qi*SSTR + kj + 8*j] = s;
      lmax = fmaxf(lmax, s);
    }
    red[qi*8 + kj] = lmax;
    __syncthreads();

    if (tid < QT){
      float mold = mrow[tid];
      float mx = mold;
      #pragma unroll
      for (int j = 0; j < 8; j++) mx = fmaxf(mx, red[tid*8 + j]);
      arow[tid] = __expf(mold - mx);
      mrow[tid] = mx;
    }
    __syncthreads();

    {
      float mloc = mrow[qi];
      float ls = 0.f;
      #pragma unroll
      for (int j = 0; j < 8; j++){
        int idx = qi*SSTR + kj + 8*j;
        float s = Ssc[idx];
        float p = __expf(s - mloc);
        Ssc[idx] = p;
        ls += p;
      }
      red[qi*8 + kj] = ls;
    }
    __syncthreads();

    if (tid < QT){
      float sum = 0.f;
      #pragma unroll
      for (int j = 0; j < 8; j++) sum += red[tid*8 + j];
      lrow[tid] = lrow[tid]*arow[tid] + sum;
    }
    {
      float alpha = arow[qi];
      #pragma unroll
      for (int i = 0; i < 16; i++) O[i] *= alpha;
      for (int kl = 0; kl < KT; kl++){
        float p = Ssc[qi*SSTR + kl];
        float vf[16];
        unpack8(&Vs[kl*KSTR + dseg], vf);
        unpack8(&Vs[kl*KSTR + dseg + 8], vf + 8);
        #pragma unroll
        for (int i = 0; i < 16; i++) O[i] += p * vf[i];
      }
    }
    __syncthreads();
  }

  float m = mrow[qi], l = lrow[qi];
  float snk = sinks[h];
  float mf = fmaxf(m, snk);
  float denom = l * __expf(m - mf) + __expf(snk - mf);
  float sc = __expf(m - mf) / denom;
  size_t o = (size_t)(b*S_LEN + qg)*HID + h*HD + dseg;
  #pragma unroll
  for (int i = 0; i < 16; i++) attnbuf[o + i] = f2b(O[i] * sc);
}

// ---------------------------------------------------------------------------------------
extern "C" void kernel_launch(void* const* d_in, const int* in_sizes, int n_in,
                              void* d_out, int out_size, void* d_ws, size_t ws_size,
                              hipStream_t stream)
{
  const float* hidden = (const float*)d_in[0];
  const float* wq     = (const float*)d_in[1];
  const float* wkv    = (const float*)d_in[2];
  const float* wgate  = (const float*)d_in[3];
  const float* ape    = (const float*)d_in[4];
  const float* sinks  = (const float*)d_in[5];
  const float* wo     = (const float*)d_in[6];

  u16* qbuf    = (u16*)d_ws;                        // 8192*2048 bf16
  u16* kvbuf   = qbuf    + (size_t)TOK*HID;         // 8192*256
  u16* gatebuf = kvbuf   + (size_t)TOK*256;         // 8192*256
  u16* krot    = gatebuf + (size_t)TOK*256;         // 2*1024*128
  u16* vbuf    = krot    + (size_t)2*NW*HD;         // 2*1024*128
  u16* attnbuf = vbuf    + (size_t)2*NW*HD;         // 8192*2048

  gemm_any<float,u16><<<dim3(HID/128, TOK/128), 256, 0, stream>>>(hidden, wq,    qbuf,    TOK, HID, HID);
  gemm_any<float,u16><<<dim3(256/128, TOK/128), 256, 0, stream>>>(hidden, wkv,   kvbuf,   TOK, 256, HID);
  gemm_any<float,u16><<<dim3(256/128, TOK/128), 256, 0, stream>>>(hidden, wgate, gatebuf, TOK, 256, HID);
  rope_q_kernel<<<(TOK*NHEAD*32)/256, 256, 0, stream>>>(qbuf);
  pool_rope_k<<<dim3(NW, 2), 128, 0, stream>>>(kvbuf, gatebuf, ape, krot, vbuf);
  attn_kernel<<<dim3(S_LEN/QT, NHEAD, 2), 256, 0, stream>>>(qbuf, krot, vbuf, sinks, attnbuf);
  // OUTPUT IS F32 (reference returns float32).
  gemm_any<u16,float><<<dim3(HID/128, TOK/128), 256, 0, stream>>>(attnbuf, wo, (float*)d_out, TOK, HID, HID);
}